// Round 5
// baseline (104.935 us; speedup 1.0000x reference)
//
#include <hip/hip_runtime.h>
#include <stdint.h>

#define NUM_ACT 6
#define NUM_OPP 3
#define NUM_SAMPLE 80
#define BATCH 4096
#define DIM 512
#define ACC_STRIDE 98304   /* BATCH*24 */
#define TROWS 32

// ---------------- JAX threefry2x32 (key = (0, 42)) ----------------
__device__ __forceinline__ uint32_t rotl32(uint32_t x, int d) {
  return (x << d) | (x >> (32 - d));
}

__device__ __forceinline__ void tf_round4(uint32_t& x0, uint32_t& x1,
                                          int r0, int r1, int r2, int r3) {
  x0 += x1; x1 = rotl32(x1, r0); x1 ^= x0;
  x0 += x1; x1 = rotl32(x1, r1); x1 ^= x0;
  x0 += x1; x1 = rotl32(x1, r2); x1 ^= x0;
  x0 += x1; x1 = rotl32(x1, r3); x1 ^= x0;
}

__device__ __forceinline__ void threefry2x32(uint32_t k0, uint32_t k1,
                                             uint32_t& x0, uint32_t& x1) {
  const uint32_t ks2 = k0 ^ k1 ^ 0x1BD11BDAu;
  x0 += k0;  x1 += k1;
  tf_round4(x0, x1, 13, 15, 26, 6);  x0 += k1;  x1 += ks2 + 1u;
  tf_round4(x0, x1, 17, 29, 16, 24); x0 += ks2; x1 += k0  + 2u;
  tf_round4(x0, x1, 13, 15, 26, 6);  x0 += k0;  x1 += k1  + 3u;
  tf_round4(x0, x1, 17, 29, 16, 24); x0 += k1;  x1 += ks2 + 4u;
  tf_round4(x0, x1, 13, 15, 26, 6);  x0 += ks2; x1 += k0  + 5u;
}

__device__ __forceinline__ float jax_uniform(uint32_t flat_idx) {
  uint32_t x0 = 0u, x1 = flat_idx;
  threefry2x32(0u, 42u, x0, x1);
  uint32_t bits = x0 ^ x1;
  return __uint_as_float((bits >> 9) | 0x3f800000u) - 1.0f;   // [0,1)
}

__device__ __forceinline__ void dot4(float& a, float4 u, float4 v) {
  a = fmaf(u.x, v.x, a); a = fmaf(u.y, v.y, a);
  a = fmaf(u.z, v.z, a); a = fmaf(u.w, v.w, a);
}

// ---------------- K1: split-K tiled GEMM -> per-chunk partials ----------------
// NO device fences anywhere (R3: agent fences forced L2 writebacks, 126us k3).
template<int NCH>
__global__ __launch_bounds__(128) void k1_gemm(
    const float* __restrict__ x, const float* __restrict__ Wopp,
    const float* __restrict__ W, float* __restrict__ part,
    float* __restrict__ ent_slots) {
  constexpr int WIDTH = 512 / NCH;
  constexpr int XSTR = WIDTH + 4;
  const int tile = blockIdx.x / NCH;
  const int ch = blockIdx.x % NCH;
  const int rowbase = tile * TROWS;
  const int dbase = ch * WIDTH;
  __shared__ float xs[TROWS * XSTR];
  __shared__ float wt[24 * XSTR];
  const int t = threadIdx.x;

  for (int f = t; f < TROWS * (WIDTH / 4); f += 128) {
    int row = f / (WIDTH / 4), c4 = (f % (WIDTH / 4)) << 2;
    float4 v = *(const float4*)(x + (size_t)(rowbase + row) * DIM + dbase + c4);
    *(float4*)(xs + row * XSTR + c4) = v;
  }
  for (int i = t; i < 24 * WIDTH; i += 128) {
    int c = i % 24, dd = i / 24;
    int d = dbase + dd;
    float v = (c < 18) ? Wopp[(c / 6) * (DIM * 6) + d * 6 + (c % 6)]
                       : W[d * 6 + (c - 18)];
    wt[c * XSTR + dd] = v;
  }
  __syncthreads();

  const int rowg = t >> 3, colg = t & 7;
  float acc[2][3] = {{0.f, 0.f, 0.f}, {0.f, 0.f, 0.f}};
  const float* xp = xs + (rowg * 2) * XSTR;
  const float* wp = wt + (colg * 3) * XSTR;
#pragma unroll 4
  for (int dd = 0; dd < WIDTH; dd += 4) {
    float4 x0 = *(const float4*)(xp + dd);
    float4 x1 = *(const float4*)(xp + XSTR + dd);
    float4 w0 = *(const float4*)(wp + dd);
    float4 w1 = *(const float4*)(wp + XSTR + dd);
    float4 w2 = *(const float4*)(wp + 2 * XSTR + dd);
    dot4(acc[0][0], x0, w0); dot4(acc[0][1], x0, w1); dot4(acc[0][2], x0, w2);
    dot4(acc[1][0], x1, w0); dot4(acc[1][1], x1, w1); dot4(acc[1][2], x1, w2);
  }
  const int r0 = rowbase + rowg * 2, c0 = colg * 3;
  float* p = part + (size_t)ch * ACC_STRIDE;
#pragma unroll
  for (int rr = 0; rr < 2; rr++)
#pragma unroll
    for (int cc = 0; cc < 3; cc++)
      p[(r0 + rr) * 24 + c0 + cc] = acc[rr][cc];
  if (blockIdx.x == 0 && t < 64) ent_slots[t] = 0.f;   // visible at kernel boundary
}

// ---------------- K3: softmax+dist+entropy + CDF sample + agent + output -----
template<int NCH>
__global__ __launch_bounds__(256) void k3_fused(
    const float* __restrict__ part, const float* __restrict__ bopp,
    const float* __restrict__ W, const float* __restrict__ bias,
    float* __restrict__ ent_slots, float* __restrict__ dout) {
  int b = blockIdx.x;
  int t = threadIdx.x;
  __shared__ float s_dist[NUM_OPP][NUM_ACT];
  __shared__ float s_xw[NUM_ACT];
  __shared__ float s_bias[NUM_ACT];
  __shared__ float s_W2[NUM_OPP * NUM_ACT][NUM_ACT];
  __shared__ int   s_act[NUM_OPP][NUM_SAMPLE];
  __shared__ float s_prob[NUM_OPP][NUM_SAMPLE];

  // ---- Phase A (one barrier): disjoint thread ranges ----
  if (t < 3) {
    // full row t: logits from partials -> softmax -> dist + entropy
    float l[NUM_ACT];
#pragma unroll
    for (int a = 0; a < NUM_ACT; a++) {
      float s = bopp[t * 6 + a];
#pragma unroll
      for (int ch = 0; ch < NCH; ch++)
        s += part[ch * ACC_STRIDE + b * 24 + t * 6 + a];
      l[a] = s;
    }
    float m = l[0];
#pragma unroll
    for (int a = 1; a < NUM_ACT; a++) m = fmaxf(m, l[a]);
    float e[NUM_ACT], Z = 0.f;
#pragma unroll
    for (int a = 0; a < NUM_ACT; a++) { e[a] = expf(l[a] - m); Z += e[a]; }
    float logZ = logf(Z);
    float H = 0.f;
#pragma unroll
    for (int a = 0; a < NUM_ACT; a++) {
      float pa = e[a] / Z;
      s_dist[t][a] = pa;
      dout[BATCH * NUM_ACT + (t * BATCH + b) * NUM_ACT + a] = pa;
      H -= pa * ((l[a] - m) - logZ);
    }
    atomicAdd(&ent_slots[b & 63], H);
  } else if (t >= 64 && t < 64 + NUM_ACT) {
    int a = t - 64;
    float s = 0.f;
#pragma unroll
    for (int ch = 0; ch < NCH; ch++)
      s += part[ch * ACC_STRIDE + b * 24 + 18 + a];
    s_xw[a] = s;
    s_bias[a] = bias[a];
  } else if (t >= 128 && t < 128 + 108) {
    int i = t - 128;
    s_W2[i / 6][i % 6] = W[DIM * NUM_ACT + i];
  }
  __syncthreads();

  // ---- Sampling via inverse CDF: 1 threefry per sample ----
  if (t < NUM_OPP * NUM_SAMPLE) {
    int k = t / NUM_SAMPLE, s = t - k * NUM_SAMPLE;
    float u = jax_uniform((uint32_t)(k * NUM_SAMPLE + s) * BATCH + (uint32_t)b);
    float c = s_dist[k][0];
    int sel = 0;
#pragma unroll
    for (int a = 1; a < NUM_ACT; a++) {
      sel += (u >= c) ? 1 : 0;
      c += s_dist[k][a];
    }
    s_act[k][s] = sel;
    s_prob[k][s] = s_dist[k][sel];
  }
  __syncthreads();

  // ---- Tail: wave 0 only, shuffle-based, no more barriers ----
  if (t < 64) {
    float p1a = s_prob[0][t] * s_prob[1][t] * s_prob[2][t];
    const bool hasb = t < (NUM_SAMPLE - 64);
    float p1b = 0.f;
    if (hasb) p1b = s_prob[0][t + 64] * s_prob[1][t + 64] * s_prob[2][t + 64];
    float tot = p1a + p1b;
#pragma unroll
    for (int m = 32; m > 0; m >>= 1) tot += __shfl_xor(tot, m);

    float o[NUM_ACT];
#pragma unroll
    for (int a = 0; a < NUM_ACT; a++) o[a] = 0.f;

    {
      float w = p1a / tot;
      int a0 = s_act[0][t], a1 = s_act[1][t], a2 = s_act[2][t];
      float la[NUM_ACT];
#pragma unroll
      for (int a = 0; a < NUM_ACT; a++)
        la[a] = s_xw[a] + s_W2[a0][a] + s_W2[6 + a1][a] + s_W2[12 + a2][a] + s_bias[a];
      float m = la[0];
#pragma unroll
      for (int a = 1; a < NUM_ACT; a++) m = fmaxf(m, la[a]);
      float e[NUM_ACT], Z = 0.f;
#pragma unroll
      for (int a = 0; a < NUM_ACT; a++) { e[a] = expf(la[a] - m); Z += e[a]; }
      float wz = w / Z;
#pragma unroll
      for (int a = 0; a < NUM_ACT; a++) o[a] = wz * e[a];
    }
    if (hasb) {
      int s2 = t + 64;
      float w = p1b / tot;
      int a0 = s_act[0][s2], a1 = s_act[1][s2], a2 = s_act[2][s2];
      float la[NUM_ACT];
#pragma unroll
      for (int a = 0; a < NUM_ACT; a++)
        la[a] = s_xw[a] + s_W2[a0][a] + s_W2[6 + a1][a] + s_W2[12 + a2][a] + s_bias[a];
      float m = la[0];
#pragma unroll
      for (int a = 1; a < NUM_ACT; a++) m = fmaxf(m, la[a]);
      float e[NUM_ACT], Z = 0.f;
#pragma unroll
      for (int a = 0; a < NUM_ACT; a++) { e[a] = expf(la[a] - m); Z += e[a]; }
      float wz = w / Z;
#pragma unroll
      for (int a = 0; a < NUM_ACT; a++) o[a] += wz * e[a];
    }
#pragma unroll
    for (int m = 32; m > 0; m >>= 1)
#pragma unroll
      for (int a = 0; a < NUM_ACT; a++) o[a] += __shfl_xor(o[a], m);
    if (t == 0) {
#pragma unroll
      for (int a = 0; a < NUM_ACT; a++) dout[b * NUM_ACT + a] = o[a];
    }
  }
}

// ---------------- K4: entropy scalar (64 slots -> 1) ----------------
__global__ __launch_bounds__(64) void k4_ent(
    const float* __restrict__ ent_slots, float* __restrict__ dout) {
  float v = ent_slots[threadIdx.x];
#pragma unroll
  for (int m = 32; m > 0; m >>= 1) v += __shfl_xor(v, m);
  if (threadIdx.x == 0)
    dout[BATCH * NUM_ACT + NUM_OPP * BATCH * NUM_ACT] = v * (1.0f / 12288.0f);
}

extern "C" void kernel_launch(void* const* d_in, const int* in_sizes, int n_in,
                              void* d_out, int out_size, void* d_ws, size_t ws_size,
                              hipStream_t stream) {
  const float* x    = (const float*)d_in[0];
  const float* Wopp = (const float*)d_in[1];
  const float* bopp = (const float*)d_in[2];
  const float* W    = (const float*)d_in[3];
  const float* bias = (const float*)d_in[4];
  float* out = (float*)d_out;
  float* part = (float*)d_ws;

  size_t need8 = ((size_t)8 * ACC_STRIDE + 64) * sizeof(float);
  if (ws_size >= need8) {
    float* ent_slots = part + (size_t)8 * ACC_STRIDE;
    k1_gemm<8><<<128 * 8, 128, 0, stream>>>(x, Wopp, W, part, ent_slots);
    k3_fused<8><<<BATCH, 256, 0, stream>>>(part, bopp, W, bias, ent_slots, out);
    k4_ent<<<1, 64, 0, stream>>>(ent_slots, out);
  } else {
    float* ent_slots = part + (size_t)4 * ACC_STRIDE;
    k1_gemm<4><<<128 * 4, 128, 0, stream>>>(x, Wopp, W, part, ent_slots);
    k3_fused<4><<<BATCH, 256, 0, stream>>>(part, bopp, W, bias, ent_slots, out);
    k4_ent<<<1, 64, 0, stream>>>(ent_slots, out);
  }
}